// Round 11
// baseline (121.053 us; speedup 1.0000x reference)
//
#include <hip/hip_runtime.h>
#include <math.h>

#define NB 8
#define NQ 512
#define NK 512
#define NH 64
#define ND 256
#define QT 4     // q rows per attn block (halved: occupancy experiment)

typedef float f32x2 __attribute__((ext_vector_type(2)));
typedef float f32x4 __attribute__((ext_vector_type(4)));

#define EXP2(x) __builtin_amdgcn_exp2f(x)
#define RCP(x)  __builtin_amdgcn_rcpf(x)
#define SCALE2 2.8853900817779268f   // 2*log2(e) folded into projections
#define LOG2E  1.4426950408889634f

static __device__ __forceinline__ f32x2 sp2(float v) { return (f32x2){v, v}; }
static __device__ __forceinline__ f32x2 fma2(f32x2 a, f32x2 b, f32x2 c) {
    return __builtin_elementwise_fma(a, b, c);
}
static __device__ __forceinline__ f32x2 mk2(float x, float y) {
    return (f32x2){x, y};
}

// 4-way-rcp additive-attention partial: acc += N4/D4 over a 4-h group,
// packed over 2 adjacent k. eq/fq/w01 are wave-uniform scalars (SGPRs).
static __device__ __forceinline__ void score4(
    const f32x2 k0, const f32x2 k1, const f32x2 k2, const f32x2 k3,
    const f32x4 eqv, const f32x4 fqv, const float w01a, const float w01b,
    f32x2& acc)
{
    const f32x2 t0 = k0 * eqv.x;
    const f32x2 t1 = k1 * eqv.y;
    const f32x2 ua = t0 + t1 + 1.0f;
    const f32x2 da = fma2(t0, t1, ua);
    f32x2 na = fma2(k0, sp2(fqv.x), sp2(w01a));
    na = fma2(k1, sp2(fqv.y), na);
    const f32x2 t2 = k2 * eqv.z;
    const f32x2 t3 = k3 * eqv.w;
    const f32x2 ub = t2 + t3 + 1.0f;
    const f32x2 db = fma2(t2, t3, ub);
    f32x2 nb = fma2(k2, sp2(fqv.z), sp2(w01b));
    nb = fma2(k3, sp2(fqv.w), nb);
    const f32x2 D = da * db;
    f32x2 N = na * db;
    N = fma2(nb, da, N);
    const f32x2 rD = mk2(RCP(D.x), RCP(D.y));
    acc = fma2(N, rD, acc);
}

// ---------------- projection + exp2:
//  q rows -> qside[row][hc][{eq0..3, fq0..3}]  (fq = w_v[h^1]*eq), 32B units
//  k rows -> Ekp[b][h][k] (transposed)
// block 0 also emits w01g[32] (pairwise w sums) and wsumg (sum of w_v).
__global__ __launch_bounds__(256, 4) void proj_kernel(
    const float* __restrict__ query, const float* __restrict__ key,
    const float* __restrict__ Wq, const float* __restrict__ Wk,
    const float* __restrict__ w_v,
    float* __restrict__ qside, float* __restrict__ Ekp,
    float* __restrict__ w01g, float* __restrict__ wsumg)
{
    __shared__ __align__(16) float insT[ND][12];   // 12 KB
    __shared__ float pacc[3][4][NH][2];            // 6 KB wave partials
    const int t = threadIdx.x;
    const bool isK = blockIdx.x >= 512;
    const float* __restrict__ in = isK ? key : query;
    const float* __restrict__ W  = isK ? Wk : Wq;
    const int rowbase = (blockIdx.x & 511) * 8;

    {   // stage 8 rows x 256 d, transposed
        const int r = t & 7, c = (t >> 3) * 8;
        const float* src = in + (size_t)(rowbase + r) * ND + c;
        const f32x4 v0 = *(const f32x4*)src;
        const f32x4 v1 = *(const f32x4*)(src + 4);
        insT[c + 0][r] = v0.x; insT[c + 1][r] = v0.y;
        insT[c + 2][r] = v0.z; insT[c + 3][r] = v0.w;
        insT[c + 4][r] = v1.x; insT[c + 5][r] = v1.y;
        insT[c + 6][r] = v1.z; insT[c + 7][r] = v1.w;
    }
    __syncthreads();

    const int lane = t & 63;          // lane = h
    const int w    = t >> 6;          // wave = d-quarter
    const int d0   = w * 64;

    f32x2 acc[4] = {{0.f,0.f},{0.f,0.f},{0.f,0.f},{0.f,0.f}};
    for (int dd = 0; dd < 64; ++dd) {
        const int d = d0 + dd;
        const float wv = W[(size_t)d * NH + lane];         // coalesced L2
        const f32x4 rA = *(const f32x4*)&insT[d][0];       // uniform b128
        const f32x4 rB = *(const f32x4*)&insT[d][4];
        acc[0] = fma2(mk2(rA.x, rA.y), sp2(wv), acc[0]);
        acc[1] = fma2(mk2(rA.z, rA.w), sp2(wv), acc[1]);
        acc[2] = fma2(mk2(rB.x, rB.y), sp2(wv), acc[2]);
        acc[3] = fma2(mk2(rB.z, rB.w), sp2(wv), acc[3]);
    }
    if (w > 0) {
        #pragma unroll
        for (int rp = 0; rp < 4; ++rp)
            *(f32x2*)&pacc[w - 1][rp][lane][0] = acc[rp];
    }
    __syncthreads();
    if (w == 0) {
        float e[8];
        #pragma unroll
        for (int rp = 0; rp < 4; ++rp) {
            f32x2 a = acc[rp];
            a += *(const f32x2*)&pacc[0][rp][lane][0];
            a += *(const f32x2*)&pacc[1][rp][lane][0];
            a += *(const f32x2*)&pacc[2][rp][lane][0];
            e[2 * rp] = a.x; e[2 * rp + 1] = a.y;
        }
        #pragma unroll
        for (int j = 0; j < 8; ++j) {
            const float x = fminf(fmaxf(e[j] * SCALE2, -30.f), 30.f);
            e[j] = EXP2(x);
        }
        if (!isK) {
            const float wx = w_v[lane ^ 1];
            #pragma unroll
            for (int j = 0; j < 8; ++j) {
                const int g = rowbase + j;
                float* dst = qside + ((size_t)g * 16 + (lane >> 2)) * 8 + (lane & 3);
                dst[0] = e[j];
                dst[4] = wx * e[j];
            }
        } else {
            #pragma unroll
            for (int j = 0; j < 8; ++j) {
                const int g = rowbase + j;
                const int bb = g >> 9, kk = g & 511;
                Ekp[((size_t)bb * NH + lane) * NK + kk] = e[j];
            }
        }
    }
    if (blockIdx.x == 0) {
        if (t < 32) w01g[t] = w_v[2 * t] + w_v[2 * t + 1];
        if (t == 64) {
            float s = 0.f;
            for (int h = 0; h < NH; ++h) s += w_v[h];
            wsumg[0] = s;
        }
    }
}

// ---------------- fused score + softmax + PV
// grid = NB*(NQ/QT) = 1024 blocks (XCD-swizzled), 512 threads (8 waves)
// -> 4 blocks/CU = 32 waves/CU = 100% slots.
// Score: thread = 2 adjacent k (f32x2) x 2 rows; rh = t>>8 picks row pair.
__global__ __launch_bounds__(512, 8) void attn_kernel(
    const float* __restrict__ qside, const float* __restrict__ Ekp,
    const float* __restrict__ value, const unsigned char* __restrict__ mask,
    const float* __restrict__ w01g, const float* __restrict__ wsumg,
    float* __restrict__ out)
{
    __shared__ __align__(16) float ps[QT][NK];     // 8 KB pre-normalized probs
    __shared__ __align__(16) float reds[QT][4];    // wave row-sum partials
    __shared__ __align__(16) float pacc[3][QT][ND]; // 12 KB PV partials

    const int t    = threadIdx.x;
    const int lane = t & 63;
    const int w    = t >> 6;
    // XCD-aware swizzle (1024%8==0, bijective): XCD x gets 128 consecutive
    // bids = exactly batch x -> its Ek+qside+V (~1.3MB) resident in 4MB L2.
    const int bid  = ((int)(blockIdx.x & 7) << 7) | ((int)blockIdx.x >> 3);
    const int b    = bid >> 7;
    const int q0   = (bid & 127) * QT;
    const int rh   = __builtin_amdgcn_readfirstlane(t >> 8);  // row pair 0/1
    const int kp   = t & 255;                                 // k-pair index

    const float wsumL = wsumg[0] * LOG2E;
    const float* __restrict__ qs  = qside + (size_t)(b * NQ + q0 + rh * 2) * 128;
    const float* __restrict__ ekc = Ekp + (size_t)b * NH * NK + 2 * kp;

    f32x2 eA[4], eB[4];
    #pragma unroll
    for (int j = 0; j < 4; ++j) eA[j] = *(const f32x2*)&ekc[(size_t)j * NK];
    #pragma unroll
    for (int j = 0; j < 4; ++j) eB[j] = *(const f32x2*)&ekc[(size_t)(4 + j) * NK];

    f32x2 acc[2] = {{0.f,0.f},{0.f,0.f}};

    for (int hc = 0; hc < 16; hc += 2) {
        {   // even chunk: consume eA, prefetch hc+2 into eA
            const f32x2 k0 = eA[0], k1 = eA[1], k2 = eA[2], k3 = eA[3];
            if (hc + 2 < 16) {
                #pragma unroll
                for (int j = 0; j < 4; ++j)
                    eA[j] = *(const f32x2*)&ekc[(size_t)(4 * (hc + 2) + j) * NK];
            }
            const float wa = w01g[2 * hc], wb = w01g[2 * hc + 1];
            #pragma unroll
            for (int r = 0; r < 2; ++r) {
                const f32x4 eqv = *(const f32x4*)&qs[r * 128 + hc * 8];     // s_load
                const f32x4 fqv = *(const f32x4*)&qs[r * 128 + hc * 8 + 4]; // s_load
                score4(k0, k1, k2, k3, eqv, fqv, wa, wb, acc[r]);
            }
        }
        {   // odd chunk: consume eB, prefetch hc+3 into eB
            const f32x2 k0 = eB[0], k1 = eB[1], k2 = eB[2], k3 = eB[3];
            if (hc + 3 < 16) {
                #pragma unroll
                for (int j = 0; j < 4; ++j)
                    eB[j] = *(const f32x2*)&ekc[(size_t)(4 * (hc + 3) + j) * NK];
            }
            const float wa = w01g[2 * hc + 2], wb = w01g[2 * hc + 3];
            #pragma unroll
            for (int r = 0; r < 2; ++r) {
                const f32x4 eqv = *(const f32x4*)&qs[r * 128 + (hc + 1) * 8];
                const f32x4 fqv = *(const f32x4*)&qs[r * 128 + (hc + 1) * 8 + 4];
                score4(k0, k1, k2, k3, eqv, fqv, wa, wb, acc[r]);
            }
        }
    }

    // ---- mask + exp (no max-subtraction: |score| <= sum|w_h| ~ 6.4)
    const unsigned char* __restrict__ mb =
        mask + (size_t)(b * NQ + q0 + rh * 2) * NK + 2 * kp;
    f32x2 p[2];
    #pragma unroll
    for (int r = 0; r < 2; ++r) {
        f32x2 arg = fma2(acc[r], sp2(-2.f * LOG2E), sp2(wsumL));
        const unsigned short m = *(const unsigned short*)(mb + (size_t)r * NK);
        if (m & 0x00ff) arg.x = -__builtin_inff();
        if (m & 0xff00) arg.y = -__builtin_inff();
        p[r] = mk2(EXP2(arg.x), EXP2(arg.y));
    }

    // ---- row sums: wave shuffle + cross-wave LDS (4 waves per row)
    #pragma unroll
    for (int r = 0; r < 2; ++r) {
        float s = p[r].x + p[r].y;
        #pragma unroll
        for (int off = 32; off; off >>= 1) s += __shfl_xor(s, off, 64);
        if (lane == 0) reds[rh * 2 + r][w & 3] = s;
    }
    __syncthreads();
    #pragma unroll
    for (int r = 0; r < 2; ++r) {
        const f32x4 sv = *(const f32x4*)&reds[rh * 2 + r][0];
        const float gsum = (sv.x + sv.y) + (sv.z + sv.w);
        p[r] = p[r] * RCP(gsum);
        *(f32x2*)&ps[rh * 2 + r][2 * kp] = p[r];
    }
    __syncthreads();

    // ---- PV: wave = (kq 0..3, dh 0..1); lane owns f32x2 of d
    const int kq   = w >> 1;
    const int dh   = w & 1;
    const int dcol = dh * 128 + 2 * lane;
    f32x2 a[QT];
    #pragma unroll
    for (int r = 0; r < QT; ++r) a[r] = (f32x2){0.f, 0.f};

    const float* __restrict__ vb = value + ((size_t)b * NK + kq * 128) * ND + dcol;
    for (int kk = 0; kk < 128; kk += 4) {
        const int kbase = kq * 128 + kk;
        const f32x2 v0 = *(const f32x2*)&vb[(size_t)(kk + 0) * ND];
        const f32x2 v1 = *(const f32x2*)&vb[(size_t)(kk + 1) * ND];
        const f32x2 v2 = *(const f32x2*)&vb[(size_t)(kk + 2) * ND];
        const f32x2 v3 = *(const f32x2*)&vb[(size_t)(kk + 3) * ND];
        #pragma unroll
        for (int r = 0; r < QT; ++r) {
            const f32x4 P = *(const f32x4*)&ps[r][kbase];   // uniform b128
            a[r] = fma2(sp2(P.x), v0, a[r]);
            a[r] = fma2(sp2(P.y), v1, a[r]);
            a[r] = fma2(sp2(P.z), v2, a[r]);
            a[r] = fma2(sp2(P.w), v3, a[r]);
        }
    }

    // ---- cross-wave reduce (single round, 4 rows)
    if (kq > 0) {
        #pragma unroll
        for (int r = 0; r < QT; ++r)
            *(f32x2*)&pacc[kq - 1][r][dcol] = a[r];
    }
    __syncthreads();
    if (kq == 0) {
        #pragma unroll
        for (int r = 0; r < QT; ++r) {
            f32x2 v = a[r];
            v += *(const f32x2*)&pacc[0][r][dcol];
            v += *(const f32x2*)&pacc[1][r][dcol];
            v += *(const f32x2*)&pacc[2][r][dcol];
            *(f32x2*)&out[(size_t)(b * NQ + q0 + r) * ND + dcol] = v;
        }
    }
}

extern "C" void kernel_launch(void* const* d_in, const int* in_sizes, int n_in,
                              void* d_out, int out_size, void* d_ws, size_t ws_size,
                              hipStream_t stream) {
    const float* key   = (const float*)d_in[0];
    const float* query = (const float*)d_in[1];
    const float* value = (const float*)d_in[2];
    const unsigned char* mask = (const unsigned char*)d_in[3];
    const float* Wk  = (const float*)d_in[4];
    const float* Wq  = (const float*)d_in[5];
    const float* w_v = (const float*)d_in[6];
    float* out = (float*)d_out;

    float* Ekp   = (float*)d_ws;                        // [NB, NH, NK]   1 MB
    float* qside = Ekp + (size_t)NB * NH * NK;          // [NB*NQ, 128]   2 MB
    float* w01g  = qside + (size_t)NB * NQ * 128;       // [32]
    float* wsumg = w01g + 32;                           // [1]

    proj_kernel<<<1024, 256, 0, stream>>>(query, key, Wq, Wk, w_v,
                                          qside, Ekp, w01g, wsumg);
    attn_kernel<<<NB * (NQ / QT), 512, 0, stream>>>(qside, Ekp, value, mask,
                                                    w01g, wsumg, out);
}

// Round 12
// 82.405 us; speedup vs baseline: 1.4690x; 1.4690x over previous
//
#include <hip/hip_runtime.h>
#include <math.h>

#define NB 8
#define NQ 512
#define NK 512
#define NH 64
#define ND 256
#define QT 4     // q rows per attn block (occupancy experiment, un-spilled)

typedef float f32x2 __attribute__((ext_vector_type(2)));
typedef float f32x4 __attribute__((ext_vector_type(4)));

#define EXP2(x) __builtin_amdgcn_exp2f(x)
#define RCP(x)  __builtin_amdgcn_rcpf(x)
#define SCALE2 2.8853900817779268f   // 2*log2(e) folded into projections
#define LOG2E  1.4426950408889634f

static __device__ __forceinline__ f32x2 sp2(float v) { return (f32x2){v, v}; }
static __device__ __forceinline__ f32x2 fma2(f32x2 a, f32x2 b, f32x2 c) {
    return __builtin_elementwise_fma(a, b, c);
}
static __device__ __forceinline__ f32x2 mk2(float x, float y) {
    return (f32x2){x, y};
}

// 4-way-rcp additive-attention partial: acc += N4/D4 over a 4-h group,
// packed over 2 adjacent k. eq/fq/w01 are wave-uniform scalars (SGPRs).
static __device__ __forceinline__ void score4(
    const f32x2 k0, const f32x2 k1, const f32x2 k2, const f32x2 k3,
    const f32x4 eqv, const f32x4 fqv, const float w01a, const float w01b,
    f32x2& acc)
{
    const f32x2 t0 = k0 * eqv.x;
    const f32x2 t1 = k1 * eqv.y;
    const f32x2 ua = t0 + t1 + 1.0f;
    const f32x2 da = fma2(t0, t1, ua);
    f32x2 na = fma2(k0, sp2(fqv.x), sp2(w01a));
    na = fma2(k1, sp2(fqv.y), na);
    const f32x2 t2 = k2 * eqv.z;
    const f32x2 t3 = k3 * eqv.w;
    const f32x2 ub = t2 + t3 + 1.0f;
    const f32x2 db = fma2(t2, t3, ub);
    f32x2 nb = fma2(k2, sp2(fqv.z), sp2(w01b));
    nb = fma2(k3, sp2(fqv.w), nb);
    const f32x2 D = da * db;
    f32x2 N = na * db;
    N = fma2(nb, da, N);
    const f32x2 rD = mk2(RCP(D.x), RCP(D.y));
    acc = fma2(N, rD, acc);
}

// ---------------- projection + exp2:
//  q rows -> qside[row][hc][{eq0..3, fq0..3}]  (fq = w_v[h^1]*eq), 32B units
//  k rows -> Ekp[b][h][k] (transposed)
// block 0 also emits w01g[32] (pairwise w sums) and wsumg (sum of w_v).
__global__ __launch_bounds__(256, 4) void proj_kernel(
    const float* __restrict__ query, const float* __restrict__ key,
    const float* __restrict__ Wq, const float* __restrict__ Wk,
    const float* __restrict__ w_v,
    float* __restrict__ qside, float* __restrict__ Ekp,
    float* __restrict__ w01g, float* __restrict__ wsumg)
{
    __shared__ __align__(16) float insT[ND][12];   // 12 KB
    __shared__ float pacc[3][4][NH][2];            // 6 KB wave partials
    const int t = threadIdx.x;
    const bool isK = blockIdx.x >= 512;
    const float* __restrict__ in = isK ? key : query;
    const float* __restrict__ W  = isK ? Wk : Wq;
    const int rowbase = (blockIdx.x & 511) * 8;

    {   // stage 8 rows x 256 d, transposed
        const int r = t & 7, c = (t >> 3) * 8;
        const float* src = in + (size_t)(rowbase + r) * ND + c;
        const f32x4 v0 = *(const f32x4*)src;
        const f32x4 v1 = *(const f32x4*)(src + 4);
        insT[c + 0][r] = v0.x; insT[c + 1][r] = v0.y;
        insT[c + 2][r] = v0.z; insT[c + 3][r] = v0.w;
        insT[c + 4][r] = v1.x; insT[c + 5][r] = v1.y;
        insT[c + 6][r] = v1.z; insT[c + 7][r] = v1.w;
    }
    __syncthreads();

    const int lane = t & 63;          // lane = h
    const int w    = t >> 6;          // wave = d-quarter
    const int d0   = w * 64;

    f32x2 acc[4] = {{0.f,0.f},{0.f,0.f},{0.f,0.f},{0.f,0.f}};
    for (int dd = 0; dd < 64; ++dd) {
        const int d = d0 + dd;
        const float wv = W[(size_t)d * NH + lane];         // coalesced L2
        const f32x4 rA = *(const f32x4*)&insT[d][0];       // uniform b128
        const f32x4 rB = *(const f32x4*)&insT[d][4];
        acc[0] = fma2(mk2(rA.x, rA.y), sp2(wv), acc[0]);
        acc[1] = fma2(mk2(rA.z, rA.w), sp2(wv), acc[1]);
        acc[2] = fma2(mk2(rB.x, rB.y), sp2(wv), acc[2]);
        acc[3] = fma2(mk2(rB.z, rB.w), sp2(wv), acc[3]);
    }
    if (w > 0) {
        #pragma unroll
        for (int rp = 0; rp < 4; ++rp)
            *(f32x2*)&pacc[w - 1][rp][lane][0] = acc[rp];
    }
    __syncthreads();
    if (w == 0) {
        float e[8];
        #pragma unroll
        for (int rp = 0; rp < 4; ++rp) {
            f32x2 a = acc[rp];
            a += *(const f32x2*)&pacc[0][rp][lane][0];
            a += *(const f32x2*)&pacc[1][rp][lane][0];
            a += *(const f32x2*)&pacc[2][rp][lane][0];
            e[2 * rp] = a.x; e[2 * rp + 1] = a.y;
        }
        #pragma unroll
        for (int j = 0; j < 8; ++j) {
            const float x = fminf(fmaxf(e[j] * SCALE2, -30.f), 30.f);
            e[j] = EXP2(x);
        }
        if (!isK) {
            const float wx = w_v[lane ^ 1];
            #pragma unroll
            for (int j = 0; j < 8; ++j) {
                const int g = rowbase + j;
                float* dst = qside + ((size_t)g * 16 + (lane >> 2)) * 8 + (lane & 3);
                dst[0] = e[j];
                dst[4] = wx * e[j];
            }
        } else {
            #pragma unroll
            for (int j = 0; j < 8; ++j) {
                const int g = rowbase + j;
                const int bb = g >> 9, kk = g & 511;
                Ekp[((size_t)bb * NH + lane) * NK + kk] = e[j];
            }
        }
    }
    if (blockIdx.x == 0) {
        if (t < 32) w01g[t] = w_v[2 * t] + w_v[2 * t + 1];
        if (t == 64) {
            float s = 0.f;
            for (int h = 0; h < NH; ++h) s += w_v[h];
            wsumg[0] = s;
        }
    }
}

// ---------------- fused score + softmax + PV
// grid = NB*(NQ/QT) = 1024 blocks (XCD-swizzled), 512 threads (8 waves).
// LDS 20.5 KB, VGPR target <=64 -> 4 blocks/CU = 32 waves/CU possible.
// NOTE: min-waves arg stays 4 — forcing 8 caps VGPR at 32 and spills (R11).
__global__ __launch_bounds__(512, 4) void attn_kernel(
    const float* __restrict__ qside, const float* __restrict__ Ekp,
    const float* __restrict__ value, const unsigned char* __restrict__ mask,
    const float* __restrict__ w01g, const float* __restrict__ wsumg,
    float* __restrict__ out)
{
    __shared__ __align__(16) float ps[QT][NK];      // 8 KB pre-normalized probs
    __shared__ __align__(16) float reds[QT][4];     // wave row-sum partials
    __shared__ __align__(16) float pacc[3][QT][ND]; // 12 KB PV partials

    const int t    = threadIdx.x;
    const int lane = t & 63;
    const int w    = t >> 6;
    // XCD-aware swizzle (1024%8==0, bijective): XCD x gets 128 consecutive
    // bids = exactly batch x -> its Ek+qside+V (~1.3MB) resident in 4MB L2.
    const int bid  = ((int)(blockIdx.x & 7) << 7) | ((int)blockIdx.x >> 3);
    const int b    = bid >> 7;
    const int q0   = (bid & 127) * QT;
    const int rh   = __builtin_amdgcn_readfirstlane(t >> 8);  // row pair 0/1
    const int kp   = t & 255;                                 // k-pair index

    const float wsumL = wsumg[0] * LOG2E;
    const float* __restrict__ qs  = qside + (size_t)(b * NQ + q0 + rh * 2) * 128;
    const float* __restrict__ ekc = Ekp + (size_t)b * NH * NK + 2 * kp;

    f32x2 eA[4], eB[4];
    #pragma unroll
    for (int j = 0; j < 4; ++j) eA[j] = *(const f32x2*)&ekc[(size_t)j * NK];
    #pragma unroll
    for (int j = 0; j < 4; ++j) eB[j] = *(const f32x2*)&ekc[(size_t)(4 + j) * NK];

    f32x2 acc[2] = {{0.f,0.f},{0.f,0.f}};

    for (int hc = 0; hc < 16; hc += 2) {
        {   // even chunk: consume eA, prefetch hc+2 into eA
            const f32x2 k0 = eA[0], k1 = eA[1], k2 = eA[2], k3 = eA[3];
            if (hc + 2 < 16) {
                #pragma unroll
                for (int j = 0; j < 4; ++j)
                    eA[j] = *(const f32x2*)&ekc[(size_t)(4 * (hc + 2) + j) * NK];
            }
            const float wa = w01g[2 * hc], wb = w01g[2 * hc + 1];
            #pragma unroll
            for (int r = 0; r < 2; ++r) {
                const f32x4 eqv = *(const f32x4*)&qs[r * 128 + hc * 8];     // s_load
                const f32x4 fqv = *(const f32x4*)&qs[r * 128 + hc * 8 + 4]; // s_load
                score4(k0, k1, k2, k3, eqv, fqv, wa, wb, acc[r]);
            }
        }
        {   // odd chunk: consume eB, prefetch hc+3 into eB
            const f32x2 k0 = eB[0], k1 = eB[1], k2 = eB[2], k3 = eB[3];
            if (hc + 3 < 16) {
                #pragma unroll
                for (int j = 0; j < 4; ++j)
                    eB[j] = *(const f32x2*)&ekc[(size_t)(4 * (hc + 3) + j) * NK];
            }
            const float wa = w01g[2 * hc + 2], wb = w01g[2 * hc + 3];
            #pragma unroll
            for (int r = 0; r < 2; ++r) {
                const f32x4 eqv = *(const f32x4*)&qs[r * 128 + (hc + 1) * 8];
                const f32x4 fqv = *(const f32x4*)&qs[r * 128 + (hc + 1) * 8 + 4];
                score4(k0, k1, k2, k3, eqv, fqv, wa, wb, acc[r]);
            }
        }
    }

    // ---- mask + exp (no max-subtraction: |score| <= sum|w_h| ~ 6.4)
    const unsigned char* __restrict__ mb =
        mask + (size_t)(b * NQ + q0 + rh * 2) * NK + 2 * kp;
    f32x2 p[2];
    #pragma unroll
    for (int r = 0; r < 2; ++r) {
        f32x2 arg = fma2(acc[r], sp2(-2.f * LOG2E), sp2(wsumL));
        const unsigned short m = *(const unsigned short*)(mb + (size_t)r * NK);
        if (m & 0x00ff) arg.x = -__builtin_inff();
        if (m & 0xff00) arg.y = -__builtin_inff();
        p[r] = mk2(EXP2(arg.x), EXP2(arg.y));
    }

    // ---- row sums: wave shuffle + cross-wave LDS (4 waves per row)
    #pragma unroll
    for (int r = 0; r < 2; ++r) {
        float s = p[r].x + p[r].y;
        #pragma unroll
        for (int off = 32; off; off >>= 1) s += __shfl_xor(s, off, 64);
        if (lane == 0) reds[rh * 2 + r][w & 3] = s;
    }
    __syncthreads();
    #pragma unroll
    for (int r = 0; r < 2; ++r) {
        const f32x4 sv = *(const f32x4*)&reds[rh * 2 + r][0];
        const float gsum = (sv.x + sv.y) + (sv.z + sv.w);
        p[r] = p[r] * RCP(gsum);
        *(f32x2*)&ps[rh * 2 + r][2 * kp] = p[r];
    }
    __syncthreads();

    // ---- PV: wave = (kq 0..3, dh 0..1); lane owns f32x2 of d
    const int kq   = w >> 1;
    const int dh   = w & 1;
    const int dcol = dh * 128 + 2 * lane;
    f32x2 a[QT];
    #pragma unroll
    for (int r = 0; r < QT; ++r) a[r] = (f32x2){0.f, 0.f};

    const float* __restrict__ vb = value + ((size_t)b * NK + kq * 128) * ND + dcol;
    for (int kk = 0; kk < 128; kk += 4) {
        const int kbase = kq * 128 + kk;
        const f32x2 v0 = *(const f32x2*)&vb[(size_t)(kk + 0) * ND];
        const f32x2 v1 = *(const f32x2*)&vb[(size_t)(kk + 1) * ND];
        const f32x2 v2 = *(const f32x2*)&vb[(size_t)(kk + 2) * ND];
        const f32x2 v3 = *(const f32x2*)&vb[(size_t)(kk + 3) * ND];
        #pragma unroll
        for (int r = 0; r < QT; ++r) {
            const f32x4 P = *(const f32x4*)&ps[r][kbase];   // uniform b128
            a[r] = fma2(sp2(P.x), v0, a[r]);
            a[r] = fma2(sp2(P.y), v1, a[r]);
            a[r] = fma2(sp2(P.z), v2, a[r]);
            a[r] = fma2(sp2(P.w), v3, a[r]);
        }
    }

    // ---- cross-wave reduce (single round, 4 rows)
    if (kq > 0) {
        #pragma unroll
        for (int r = 0; r < QT; ++r)
            *(f32x2*)&pacc[kq - 1][r][dcol] = a[r];
    }
    __syncthreads();
    if (kq == 0) {
        #pragma unroll
        for (int r = 0; r < QT; ++r) {
            f32x2 v = a[r];
            v += *(const f32x2*)&pacc[0][r][dcol];
            v += *(const f32x2*)&pacc[1][r][dcol];
            v += *(const f32x2*)&pacc[2][r][dcol];
            *(f32x2*)&out[(size_t)(b * NQ + q0 + r) * ND + dcol] = v;
        }
    }
}

extern "C" void kernel_launch(void* const* d_in, const int* in_sizes, int n_in,
                              void* d_out, int out_size, void* d_ws, size_t ws_size,
                              hipStream_t stream) {
    const float* key   = (const float*)d_in[0];
    const float* query = (const float*)d_in[1];
    const float* value = (const float*)d_in[2];
    const unsigned char* mask = (const unsigned char*)d_in[3];
    const float* Wk  = (const float*)d_in[4];
    const float* Wq  = (const float*)d_in[5];
    const float* w_v = (const float*)d_in[6];
    float* out = (float*)d_out;

    float* Ekp   = (float*)d_ws;                        // [NB, NH, NK]   1 MB
    float* qside = Ekp + (size_t)NB * NH * NK;          // [NB*NQ, 128]   2 MB
    float* w01g  = qside + (size_t)NB * NQ * 128;       // [32]
    float* wsumg = w01g + 32;                           // [1]

    proj_kernel<<<1024, 256, 0, stream>>>(query, key, Wq, Wk, w_v,
                                          qside, Ekp, w01g, wsumg);
    attn_kernel<<<NB * (NQ / QT), 512, 0, stream>>>(qside, Ekp, value, mask,
                                                    w01g, wsumg, out);
}

// Round 13
// 73.495 us; speedup vs baseline: 1.6471x; 1.1212x over previous
//
#include <hip/hip_runtime.h>
#include <math.h>

#define NB 8
#define NQ 512
#define NK 512
#define NH 64
#define ND 256
#define QT 8     // q rows per attn block (R10 tile; waves doubled inside block)

typedef float f32x2 __attribute__((ext_vector_type(2)));
typedef float f32x4 __attribute__((ext_vector_type(4)));

#define EXP2(x) __builtin_amdgcn_exp2f(x)
#define RCP(x)  __builtin_amdgcn_rcpf(x)
#define SCALE2 2.8853900817779268f   // 2*log2(e) folded into projections
#define LOG2E  1.4426950408889634f

static __device__ __forceinline__ f32x2 sp2(float v) { return (f32x2){v, v}; }
static __device__ __forceinline__ f32x2 fma2(f32x2 a, f32x2 b, f32x2 c) {
    return __builtin_elementwise_fma(a, b, c);
}
static __device__ __forceinline__ f32x2 mk2(float x, float y) {
    return (f32x2){x, y};
}

// 4-way-rcp additive-attention partial: acc += N4/D4 over a 4-h group,
// packed over 2 adjacent k. eq/fq/w01 are wave-uniform scalars (SGPRs).
static __device__ __forceinline__ void score4(
    const f32x2 k0, const f32x2 k1, const f32x2 k2, const f32x2 k3,
    const f32x4 eqv, const f32x4 fqv, const float w01a, const float w01b,
    f32x2& acc)
{
    const f32x2 t0 = k0 * eqv.x;
    const f32x2 t1 = k1 * eqv.y;
    const f32x2 ua = t0 + t1 + 1.0f;
    const f32x2 da = fma2(t0, t1, ua);
    f32x2 na = fma2(k0, sp2(fqv.x), sp2(w01a));
    na = fma2(k1, sp2(fqv.y), na);
    const f32x2 t2 = k2 * eqv.z;
    const f32x2 t3 = k3 * eqv.w;
    const f32x2 ub = t2 + t3 + 1.0f;
    const f32x2 db = fma2(t2, t3, ub);
    f32x2 nb = fma2(k2, sp2(fqv.z), sp2(w01b));
    nb = fma2(k3, sp2(fqv.w), nb);
    const f32x2 D = da * db;
    f32x2 N = na * db;
    N = fma2(nb, da, N);
    const f32x2 rD = mk2(RCP(D.x), RCP(D.y));
    acc = fma2(N, rD, acc);
}

// ---------------- projection + exp2:
//  q rows -> qside[row][hc][{eq0..3, fq0..3}]  (fq = w_v[h^1]*eq), 32B units
//  k rows -> Ekp[b][h][k] (transposed)
// block 0 also emits w01g[32] (pairwise w sums) and wsumg (sum of w_v).
__global__ __launch_bounds__(256, 4) void proj_kernel(
    const float* __restrict__ query, const float* __restrict__ key,
    const float* __restrict__ Wq, const float* __restrict__ Wk,
    const float* __restrict__ w_v,
    float* __restrict__ qside, float* __restrict__ Ekp,
    float* __restrict__ w01g, float* __restrict__ wsumg)
{
    __shared__ __align__(16) float insT[ND][12];   // 12 KB
    __shared__ float pacc[3][4][NH][2];            // 6 KB wave partials
    const int t = threadIdx.x;
    const bool isK = blockIdx.x >= 512;
    const float* __restrict__ in = isK ? key : query;
    const float* __restrict__ W  = isK ? Wk : Wq;
    const int rowbase = (blockIdx.x & 511) * 8;

    {   // stage 8 rows x 256 d, transposed
        const int r = t & 7, c = (t >> 3) * 8;
        const float* src = in + (size_t)(rowbase + r) * ND + c;
        const f32x4 v0 = *(const f32x4*)src;
        const f32x4 v1 = *(const f32x4*)(src + 4);
        insT[c + 0][r] = v0.x; insT[c + 1][r] = v0.y;
        insT[c + 2][r] = v0.z; insT[c + 3][r] = v0.w;
        insT[c + 4][r] = v1.x; insT[c + 5][r] = v1.y;
        insT[c + 6][r] = v1.z; insT[c + 7][r] = v1.w;
    }
    __syncthreads();

    const int lane = t & 63;          // lane = h
    const int w    = t >> 6;          // wave = d-quarter
    const int d0   = w * 64;

    f32x2 acc[4] = {{0.f,0.f},{0.f,0.f},{0.f,0.f},{0.f,0.f}};
    for (int dd = 0; dd < 64; ++dd) {
        const int d = d0 + dd;
        const float wv = W[(size_t)d * NH + lane];         // coalesced L2
        const f32x4 rA = *(const f32x4*)&insT[d][0];       // uniform b128
        const f32x4 rB = *(const f32x4*)&insT[d][4];
        acc[0] = fma2(mk2(rA.x, rA.y), sp2(wv), acc[0]);
        acc[1] = fma2(mk2(rA.z, rA.w), sp2(wv), acc[1]);
        acc[2] = fma2(mk2(rB.x, rB.y), sp2(wv), acc[2]);
        acc[3] = fma2(mk2(rB.z, rB.w), sp2(wv), acc[3]);
    }
    if (w > 0) {
        #pragma unroll
        for (int rp = 0; rp < 4; ++rp)
            *(f32x2*)&pacc[w - 1][rp][lane][0] = acc[rp];
    }
    __syncthreads();
    if (w == 0) {
        float e[8];
        #pragma unroll
        for (int rp = 0; rp < 4; ++rp) {
            f32x2 a = acc[rp];
            a += *(const f32x2*)&pacc[0][rp][lane][0];
            a += *(const f32x2*)&pacc[1][rp][lane][0];
            a += *(const f32x2*)&pacc[2][rp][lane][0];
            e[2 * rp] = a.x; e[2 * rp + 1] = a.y;
        }
        #pragma unroll
        for (int j = 0; j < 8; ++j) {
            const float x = fminf(fmaxf(e[j] * SCALE2, -30.f), 30.f);
            e[j] = EXP2(x);
        }
        if (!isK) {
            const float wx = w_v[lane ^ 1];
            #pragma unroll
            for (int j = 0; j < 8; ++j) {
                const int g = rowbase + j;
                float* dst = qside + ((size_t)g * 16 + (lane >> 2)) * 8 + (lane & 3);
                dst[0] = e[j];
                dst[4] = wx * e[j];
            }
        } else {
            #pragma unroll
            for (int j = 0; j < 8; ++j) {
                const int g = rowbase + j;
                const int bb = g >> 9, kk = g & 511;
                Ekp[((size_t)bb * NH + lane) * NK + kk] = e[j];
            }
        }
    }
    if (blockIdx.x == 0) {
        if (t < 32) w01g[t] = w_v[2 * t] + w_v[2 * t + 1];
        if (t == 64) {
            float s = 0.f;
            for (int h = 0; h < NH; ++h) s += w_v[h];
            wsumg[0] = s;
        }
    }
}

// ---------------- fused score + softmax + PV
// grid = NB*(NQ/QT) = 512 blocks (XCD-swizzled), 1024 threads (16 waves).
// LDS ~72 KB, VGPR cap 64 (bounds ,4) -> hardware can pack 2 blocks/CU
// = 32 waves/CU. Score: thread = 2 adjacent k (kp=t&255) x 2 rows (rq=t>>8).
// PV: wave = (kq 0..7, dh 0..1), 64 k-rows x 128 d-cols each; V read once.
// NOTE: min-waves arg stays 4 — 8 caps VGPR at 32 and spills (R4/R11).
__global__ __launch_bounds__(1024, 4) void attn_kernel(
    const float* __restrict__ qside, const float* __restrict__ Ekp,
    const float* __restrict__ value, const unsigned char* __restrict__ mask,
    const float* __restrict__ w01g, const float* __restrict__ wsumg,
    float* __restrict__ out)
{
    __shared__ __align__(16) float ps[QT][NK];          // 16 KB probs
    __shared__ __align__(16) float reds[QT][4];         // row-sum partials
    __shared__ __align__(16) float pacc[2][7][QT][128]; // 56 KB PV partials

    const int t    = threadIdx.x;
    const int lane = t & 63;
    const int w    = t >> 6;                   // 0..15
    // XCD-aware swizzle (512%8==0, bijective): XCD x gets 64 consecutive
    // bids = exactly batch x -> Ek+qside+V (~2.8MB) resident in its 4MB L2.
    const int bid  = ((int)(blockIdx.x & 7) << 6) | ((int)blockIdx.x >> 3);
    const int b    = bid >> 6;
    const int q0   = (bid & 63) * QT;
    const int rq   = __builtin_amdgcn_readfirstlane(t >> 8);  // row quarter 0..3
    const int kp   = t & 255;                                 // k-pair index

    const float wsumL = wsumg[0] * LOG2E;
    const float* __restrict__ qs  = qside + (size_t)(b * NQ + q0 + rq * 2) * 128;
    const float* __restrict__ ekc = Ekp + (size_t)b * NH * NK + 2 * kp;

    f32x2 eA[4], eB[4];
    #pragma unroll
    for (int j = 0; j < 4; ++j) eA[j] = *(const f32x2*)&ekc[(size_t)j * NK];
    #pragma unroll
    for (int j = 0; j < 4; ++j) eB[j] = *(const f32x2*)&ekc[(size_t)(4 + j) * NK];

    f32x2 acc[2] = {{0.f,0.f},{0.f,0.f}};

    for (int hc = 0; hc < 16; hc += 2) {
        {   // even chunk: consume eA, prefetch hc+2 into eA
            const f32x2 k0 = eA[0], k1 = eA[1], k2 = eA[2], k3 = eA[3];
            if (hc + 2 < 16) {
                #pragma unroll
                for (int j = 0; j < 4; ++j)
                    eA[j] = *(const f32x2*)&ekc[(size_t)(4 * (hc + 2) + j) * NK];
            }
            const float wa = w01g[2 * hc], wb = w01g[2 * hc + 1];
            #pragma unroll
            for (int r = 0; r < 2; ++r) {
                const f32x4 eqv = *(const f32x4*)&qs[r * 128 + hc * 8];     // s_load
                const f32x4 fqv = *(const f32x4*)&qs[r * 128 + hc * 8 + 4]; // s_load
                score4(k0, k1, k2, k3, eqv, fqv, wa, wb, acc[r]);
            }
        }
        {   // odd chunk: consume eB, prefetch hc+3 into eB
            const f32x2 k0 = eB[0], k1 = eB[1], k2 = eB[2], k3 = eB[3];
            if (hc + 3 < 16) {
                #pragma unroll
                for (int j = 0; j < 4; ++j)
                    eB[j] = *(const f32x2*)&ekc[(size_t)(4 * (hc + 3) + j) * NK];
            }
            const float wa = w01g[2 * hc + 2], wb = w01g[2 * hc + 3];
            #pragma unroll
            for (int r = 0; r < 2; ++r) {
                const f32x4 eqv = *(const f32x4*)&qs[r * 128 + (hc + 1) * 8];
                const f32x4 fqv = *(const f32x4*)&qs[r * 128 + (hc + 1) * 8 + 4];
                score4(k0, k1, k2, k3, eqv, fqv, wa, wb, acc[r]);
            }
        }
    }

    // ---- mask + exp (no max-subtraction: |score| <= sum|w_h| ~ 6.4)
    const unsigned char* __restrict__ mb =
        mask + (size_t)(b * NQ + q0 + rq * 2) * NK + 2 * kp;
    f32x2 p[2];
    #pragma unroll
    for (int r = 0; r < 2; ++r) {
        f32x2 arg = fma2(acc[r], sp2(-2.f * LOG2E), sp2(wsumL));
        const unsigned short m = *(const unsigned short*)(mb + (size_t)r * NK);
        if (m & 0x00ff) arg.x = -__builtin_inff();
        if (m & 0xff00) arg.y = -__builtin_inff();
        p[r] = mk2(EXP2(arg.x), EXP2(arg.y));
    }

    // ---- row sums: wave shuffle + cross-wave LDS (4 k-quarter waves per row)
    #pragma unroll
    for (int r = 0; r < 2; ++r) {
        float s = p[r].x + p[r].y;
        #pragma unroll
        for (int off = 32; off; off >>= 1) s += __shfl_xor(s, off, 64);
        if (lane == 0) reds[rq * 2 + r][w & 3] = s;
    }
    __syncthreads();
    #pragma unroll
    for (int r = 0; r < 2; ++r) {
        const f32x4 sv = *(const f32x4*)&reds[rq * 2 + r][0];
        const float gsum = (sv.x + sv.y) + (sv.z + sv.w);
        p[r] = p[r] * RCP(gsum);
        *(f32x2*)&ps[rq * 2 + r][2 * kp] = p[r];
    }
    __syncthreads();

    // ---- PV: wave = (kq 0..7, dh 0..1); lane owns f32x2 of d; 64 k-rows
    const int kq   = w >> 1;
    const int dh   = w & 1;
    const int dcol = dh * 128 + 2 * lane;
    f32x2 a[QT];
    #pragma unroll
    for (int r = 0; r < QT; ++r) a[r] = (f32x2){0.f, 0.f};

    const float* __restrict__ vb = value + ((size_t)b * NK + kq * 64) * ND + dcol;
    for (int kk = 0; kk < 64; kk += 4) {
        const int kbase = kq * 64 + kk;
        const f32x2 v0 = *(const f32x2*)&vb[(size_t)(kk + 0) * ND];
        const f32x2 v1 = *(const f32x2*)&vb[(size_t)(kk + 1) * ND];
        const f32x2 v2 = *(const f32x2*)&vb[(size_t)(kk + 2) * ND];
        const f32x2 v3 = *(const f32x2*)&vb[(size_t)(kk + 3) * ND];
        #pragma unroll
        for (int r = 0; r < QT; ++r) {
            const f32x4 P = *(const f32x4*)&ps[r][kbase];   // uniform b128
            a[r] = fma2(sp2(P.x), v0, a[r]);
            a[r] = fma2(sp2(P.y), v1, a[r]);
            a[r] = fma2(sp2(P.z), v2, a[r]);
            a[r] = fma2(sp2(P.w), v3, a[r]);
        }
    }

    // ---- reduce over the 8 kq waves within each dh half
    if (kq > 0) {
        #pragma unroll
        for (int r = 0; r < QT; ++r)
            *(f32x2*)&pacc[dh][kq - 1][r][2 * lane] = a[r];
    }
    __syncthreads();
    if (kq == 0) {
        #pragma unroll
        for (int r = 0; r < QT; ++r) {
            f32x2 v = a[r];
            #pragma unroll
            for (int j = 0; j < 7; ++j)
                v += *(const f32x2*)&pacc[dh][j][r][2 * lane];
            *(f32x2*)&out[(size_t)(b * NQ + q0 + r) * ND + dcol] = v;
        }
    }
}

extern "C" void kernel_launch(void* const* d_in, const int* in_sizes, int n_in,
                              void* d_out, int out_size, void* d_ws, size_t ws_size,
                              hipStream_t stream) {
    const float* key   = (const float*)d_in[0];
    const float* query = (const float*)d_in[1];
    const float* value = (const float*)d_in[2];
    const unsigned char* mask = (const unsigned char*)d_in[3];
    const float* Wk  = (const float*)d_in[4];
    const float* Wq  = (const float*)d_in[5];
    const float* w_v = (const float*)d_in[6];
    float* out = (float*)d_out;

    float* Ekp   = (float*)d_ws;                        // [NB, NH, NK]   1 MB
    float* qside = Ekp + (size_t)NB * NH * NK;          // [NB*NQ, 128]   2 MB
    float* w01g  = qside + (size_t)NB * NQ * 128;       // [32]
    float* wsumg = w01g + 32;                           // [1]

    proj_kernel<<<1024, 256, 0, stream>>>(query, key, Wq, Wk, w_v,
                                          qside, Ekp, w01g, wsumg);
    attn_kernel<<<NB * (NQ / QT), 1024, 0, stream>>>(qside, Ekp, value, mask,
                                                     w01g, wsumg, out);
}